// Round 20
// baseline (177.420 us; speedup 1.0000x reference)
//
#include <hip/hip_runtime.h>

// ---------------------------------------------------------------------------
// Motion_Grid: PE(sin/cos @ 3 freqs) -> 6 trilinear samples (3 grids) -> MLP
// Round 20: r19 main (114us; unique-line theory: 8x64x64 row-clustered bins
// cut FETCH 139->99->60MB across r18/r19) + sort pipeline on ALL 256 CUs:
// KB 128->256 chunks (hist 64KB LDS and scatter 128KB LDS both fit 1/CU) and
// u16 counts/offs (matrix stays 16MB; per-chunk bin counts <=~10, offs <=~120).
// ---------------------------------------------------------------------------

#define NB 32768     // 8(x) x 64(y) x 64(z) bins over raw x in [0,1)^3
#define KB 256       // counting/scatter chunks (= scan-matrix columns)
#define NXCD 8

typedef _Float16 f16x2 __attribute__((ext_vector_type(2)));
typedef __fp16  h8    __attribute__((ext_vector_type(8)));   // MFMA A/B frag
typedef float   f4    __attribute__((ext_vector_type(4)));   // MFMA C/D frag

__device__ __forceinline__ f16x2 pkrtz(float a, float b) {
    return __builtin_bit_cast(f16x2, __builtin_amdgcn_cvt_pkrtz(a, b));
}
__device__ __forceinline__ unsigned pkrtzu(float a, float b) {
    return __builtin_bit_cast(unsigned, __builtin_amdgcn_cvt_pkrtz(a, b));
}
__device__ __forceinline__ float fdot2(f16x2 a, f16x2 b, float c) {
    return __builtin_amdgcn_fdot2(a, b, c, false);
}
__device__ __forceinline__ f16x2 u2h(unsigned u) { return __builtin_bit_cast(f16x2, u); }

// x coarse (3b: intra-line dim), y fine (6b), z fine (6b); x-fastest order.
__device__ __forceinline__ int bin_of(float xv, float yv, float zv) {
    int qx = min(max((int)(xv * 8.f), 0), 7);
    int qy = min(max((int)(yv * 64.f), 0), 63);
    int qz = min(max((int)(zv * 64.f), 0), 63);
    return (qz << 9) | (qy << 3) | qx;
}

// ---- Fused prep: pack x-padded f16 grids | padded weights ------------------
// Padded grid layout: [z][y][xp], xp in [0,S], cell (z,y,xp) = src (z,y,max(xp-1,0)).
#define PREP_BLOCKS 9440

__global__ __launch_bounds__(256)
void prep_k(const float* __restrict__ g0, const float* __restrict__ n0,
            const float* __restrict__ g1, const float* __restrict__ n1,
            const float* __restrict__ g2, const float* __restrict__ n2,
            const float* __restrict__ w1, const float* __restrict__ w2,
            uint2* __restrict__ p0, uint2* __restrict__ p1,
            unsigned* __restrict__ p2,
            unsigned short* __restrict__ w1p, unsigned short* __restrict__ w2p) {
    const int b = blockIdx.x, t = threadIdx.x;
    if (b < 8256) {                      // grid2: 128*128*129 padded cells
        int i = b * 256 + t;
        if (i < 2113536) {
            int z = i / 16512, rem = i % 16512;
            int y = rem / 129, xp = rem % 129;
            int v = (z * 128 + y) * 128 + max(xp - 1, 0);
            p2[i] = pkrtzu(g2[v] + n2[v], g2[2097152 + v] + n2[2097152 + v]);
        }
    } else if (b < 9296) {               // grid1: 64*64*65 padded cells
        int i = (b - 8256) * 256 + t;
        if (i < 266240) {
            int z = i / 4160, rem = i % 4160;
            int y = rem / 65, xp = rem % 65;
            int v = (z * 64 + y) * 64 + max(xp - 1, 0);
            uint2 r;
            r.x = pkrtzu(g1[v] + n1[v], g1[262144 + v] + n1[262144 + v]);
            r.y = pkrtzu(g1[524288 + v] + n1[524288 + v], g1[786432 + v] + n1[786432 + v]);
            p1[i] = r;
        }
    } else if (b < 9428) {               // grid0: 32*32*33 padded cells
        int i = (b - 9296) * 256 + t;
        if (i < 33792) {
            int z = i / 1056, rem = i % 1056;
            int y = rem / 33, xp = rem % 33;
            int v = (z * 32 + y) * 32 + max(xp - 1, 0);
            uint2 r;
            r.x = pkrtzu(g0[v] + n0[v], g0[32768 + v] + n0[32768 + v]);
            r.y = pkrtzu(g0[65536 + v] + n0[65536 + v], g0[98304 + v] + n0[98304 + v]);
            p0[i] = r;
        }
    } else {                             // weights: 2048 + 1024 halves
        int i = (b - 9428) * 256 + t;
        if (i < 2048) {                  // w1p[j][k], K padded 20->32
            int j = i >> 5, k = i & 31;
            float v = (k < 20) ? w1[j * 20 + k] : 0.f;
            w1p[i] = __builtin_bit_cast(unsigned short, (_Float16)v);
        } else if (i < 3072) {           // w2p[o][jj], M padded 7->16
            int i2 = i - 2048;
            int o = i2 >> 6, jj = i2 & 63;
            float v = (o < 7) ? w2[o * 64 + jj] : 0.f;
            w2p[i2] = __builtin_bit_cast(unsigned short, (_Float16)v);
        }
    }
}

// ---- Histogram: dual-u16 LDS counters (64 KB), u16 output ------------------
__global__ __launch_bounds__(1024)
void hist_k(const float* __restrict__ x, unsigned short* __restrict__ counts,
            int npts) {
    __shared__ unsigned h32[NB / 2];   // 64 KB: two u16 counters per uint
    const int t = threadIdx.x, b = blockIdx.x;
    for (int i = t; i < NB / 2; i += 1024) h32[i] = 0u;
    __syncthreads();
    const int chunk = (npts + KB - 1) / KB;
    const int s = b * chunk, e = min(s + chunk, npts);
    for (int p = s + t; p < e; p += 1024) {
        int bin = bin_of(x[3 * p], x[3 * p + 1], x[3 * p + 2]);
        atomicAdd(&h32[bin >> 1], 1u << ((bin & 1) * 16));  // LDS atomic
    }
    __syncthreads();
    for (int i = t; i < NB; i += 1024)
        counts[(size_t)b * NB + i] =
            (unsigned short)((h32[i >> 1] >> ((i & 1) * 16)) & 0xffffu);
}

// ---- Cross-block scan, LDS-tiled, IN-PLACE (offs == counts, u16). ----------
__global__ __launch_bounds__(256)
void scan_rows_k(unsigned short* __restrict__ counts, int* __restrict__ rowsum) {
    __shared__ unsigned short tile[KB][32];   // 16 KB
    const int g = blockIdx.x, t = threadIdx.x;
    for (int idx = t; idx < KB * 32; idx += 256) {
        int b = idx >> 5, j = idx & 31;
        tile[b][j] = counts[(size_t)b * NB + g * 32 + j];
    }
    __syncthreads();
    if (t < 32) {
        int run = 0;
#pragma unroll 8
        for (int b = 0; b < KB; ++b) {
            int v = tile[b][t];
            tile[b][t] = (unsigned short)run;   // offs fits u16 (bin total ~120)
            run += v;
        }
        rowsum[g * 32 + t] = run;
    }
    __syncthreads();
    for (int idx = t; idx < KB * 32; idx += 256) {
        int b = idx >> 5, j = idx & 31;
        counts[(size_t)b * NB + g * 32 + j] = tile[b][j];   // in-place exclusive
    }
}

// ---- Scatter: shfl-based top-scan of rowsum + LDS-ranked scatter -----------
__global__ __launch_bounds__(1024)
void scatter_k(const float* __restrict__ x, const unsigned short* __restrict__ offs,
               const int* __restrict__ rowsum, float4* __restrict__ sorted,
               int npts) {
    __shared__ int base[NB];     // 128 KB
    __shared__ int wsum[16];
    const int t = threadIdx.x, b = blockIdx.x;
    const int lane = t & 63;

    // binbase = exclusive scan of rowsum[NB], 32 entries/thread, wave-scan.
    const int t32 = t * 32;
    int s32 = 0;
    for (int i = 0; i < 32; ++i) s32 += rowsum[t32 + i];
    int inc = s32;
    for (int d = 1; d < 64; d <<= 1) {
        int o = __shfl_up(inc, d, 64);
        if (lane >= d) inc += o;
    }
    if (lane == 63) wsum[t >> 6] = inc;
    __syncthreads();
    if (t == 0) {
        int acc = 0;
        for (int i = 0; i < 16; ++i) { int v = wsum[i]; wsum[i] = acc; acc += v; }
    }
    __syncthreads();
    int run = wsum[t >> 6] + inc - s32;
    for (int i = 0; i < 32; ++i) {
        int v = rowsum[t32 + i];
        base[t32 + i] = run;
        run += v;
    }
    __syncthreads();
    for (int i = t; i < NB; i += 1024)
        base[i] += (int)offs[(size_t)b * NB + i];   // coalesced u16 reads
    __syncthreads();

    const int chunk = (npts + KB - 1) / KB;
    const int s = b * chunk, e = min(s + chunk, npts);
    for (int p = s + t; p < e; p += 1024) {
        float xv = x[3 * p], yv = x[3 * p + 1], zv = x[3 * p + 2];
        int pos = atomicAdd(&base[bin_of(xv, yv, zv)], 1);  // LDS atomic
        float4 v; v.x = xv; v.y = yv; v.z = zv; v.w = __int_as_float(p);
        sorted[pos] = v;
    }
}

// ---- Trilinear gather on x-padded grid, fused row-pair loads ---------------
template<int S>
__device__ __forceinline__ void tl_setup(float cx, float cy, float cz,
        int& o00, int& o01, int& o10, int& o11,
        f16x2& w00, f16x2& w01, f16x2& w10, f16x2& w11) {
    const float hs = (float)S * 0.5f;
    float gx = fmaf(cx, hs, hs - 0.5f);
    float gy = fmaf(cy, hs, hs - 0.5f);
    float gz = fmaf(cz, hs, hs - 0.5f);
    float fx = floorf(gx), fy = floorf(gy), fz = floorf(gz);
    float tx = gx - fx, ty = gy - fy, tz = gz - fz;
    int x0 = (int)fx, y0 = (int)fy, z0 = (int)fz;
    float wx0 = (1.f - tx) * ((x0 >= 0)    ? 1.f : 0.f);
    float wx1 = tx         * ((x0 + 1 < S) ? 1.f : 0.f);
    float wy0 = (1.f - ty) * ((y0 >= 0)    ? 1.f : 0.f);
    float wy1 = ty         * ((y0 + 1 < S) ? 1.f : 0.f);
    float wz0 = (1.f - tz) * ((z0 >= 0)    ? 1.f : 0.f);
    float wz1 = tz         * ((z0 + 1 < S) ? 1.f : 0.f);
    const int xb = x0 + 1;                 // padded-x index, always valid
    f16x2 wx2 = pkrtz(wx0, wx1);
    int ys0 = max(y0, 0), ys1 = min(y0 + 1, S - 1);
    int zs0 = max(z0, 0), zs1 = min(z0 + 1, S - 1);
    o00 = (zs0 * S + ys0) * (S + 1) + xb;
    o01 = (zs0 * S + ys1) * (S + 1) + xb;
    o10 = (zs1 * S + ys0) * (S + 1) + xb;
    o11 = (zs1 * S + ys1) * (S + 1) + xb;
    float a00 = wz0 * wy0, a01 = wz0 * wy1, a10 = wz1 * wy0, a11 = wz1 * wy1;
    w00 = pkrtz(a00, a00) * wx2;
    w01 = pkrtz(a01, a01) * wx2;
    w10 = pkrtz(a10, a10) * wx2;
    w11 = pkrtz(a11, a11) * wx2;
}

struct TL4S {
    uint4 r00, r01, r10, r11;
    f16x2 w00, w01, w10, w11;
};
template<int S>
__device__ __forceinline__ TL4S tl4_issue(const uint2* __restrict__ vol,
                                          float cx, float cy, float cz) {
    TL4S r; int o00, o01, o10, o11;
    tl_setup<S>(cx, cy, cz, o00, o01, o10, o11, r.w00, r.w01, r.w10, r.w11);
    r.r00 = *reinterpret_cast<const uint4*>(vol + o00);
    r.r01 = *reinterpret_cast<const uint4*>(vol + o01);
    r.r10 = *reinterpret_cast<const uint4*>(vol + o10);
    r.r11 = *reinterpret_cast<const uint4*>(vol + o11);
    return r;
}
#define TL4_ROW(s, R, WP, f) { uint4 r = (s).R; \
    unsigned pc0 = __builtin_amdgcn_perm(r.z, r.x, 0x05040100u); \
    unsigned pc1 = __builtin_amdgcn_perm(r.z, r.x, 0x07060302u); \
    unsigned pc2 = __builtin_amdgcn_perm(r.w, r.y, 0x05040100u); \
    unsigned pc3 = __builtin_amdgcn_perm(r.w, r.y, 0x07060302u); \
    (f)[0] = fdot2((s).WP, u2h(pc0), (f)[0]); (f)[1] = fdot2((s).WP, u2h(pc1), (f)[1]); \
    (f)[2] = fdot2((s).WP, u2h(pc2), (f)[2]); (f)[3] = fdot2((s).WP, u2h(pc3), (f)[3]); }
__device__ __forceinline__ void tl4_consume(const TL4S& s, float* f) {
    TL4_ROW(s, r00, w00, f) TL4_ROW(s, r01, w01, f)
    TL4_ROW(s, r10, w10, f) TL4_ROW(s, r11, w11, f)
}

struct TL2S {
    uint2 r00, r01, r10, r11;
    f16x2 w00, w01, w10, w11;
};
template<int S>
__device__ __forceinline__ TL2S tl2_issue(const unsigned* __restrict__ vol,
                                          float cx, float cy, float cz) {
    TL2S r; int o00, o01, o10, o11;
    tl_setup<S>(cx, cy, cz, o00, o01, o10, o11, r.w00, r.w01, r.w10, r.w11);
    r.r00 = *reinterpret_cast<const uint2*>(vol + o00);
    r.r01 = *reinterpret_cast<const uint2*>(vol + o01);
    r.r10 = *reinterpret_cast<const uint2*>(vol + o10);
    r.r11 = *reinterpret_cast<const uint2*>(vol + o11);
    return r;
}
#define TL2_ROW(s, R, WP, f) { uint2 r = (s).R; \
    unsigned pc0 = __builtin_amdgcn_perm(r.y, r.x, 0x05040100u); \
    unsigned pc1 = __builtin_amdgcn_perm(r.y, r.x, 0x07060302u); \
    (f)[0] = fdot2((s).WP, u2h(pc0), (f)[0]); (f)[1] = fdot2((s).WP, u2h(pc1), (f)[1]); }
__device__ __forceinline__ void tl2_consume(const TL2S& s, float* f) {
    TL2_ROW(s, r00, w00, f) TL2_ROW(s, r01, w01, f)
    TL2_ROW(s, r10, w10, f) TL2_ROW(s, r11, w11, f)
}

__device__ __forceinline__ void trig3(float x, float y, float z,
        float* s1, float* c1, float* s2, float* c2, float* s4, float* c4) {
    const float v[3] = {x, y, z};
#pragma unroll
    for (int d = 0; d < 3; ++d) {
        float sa = __builtin_amdgcn_sinf(0.5f * v[d]);
        float ca = __builtin_amdgcn_cosf(0.5f * v[d]);
        s1[d] = sa; c1[d] = ca;
        float sb = 2.f * sa * ca, cb = fmaf(-2.f * sa, sa, 1.f);
        s2[d] = sb; c2[d] = cb;
        s4[d] = 2.f * sb * cb; c4[d] = fmaf(-2.f * sb, sb, 1.f);
    }
}

// ---- Main: 1 pt/thread, per-wave MFMA MLP, wave-local LDS (r19 exact) ------
// Per-wave LDS 7424 B: fbuf [0,5120) 64x80B | hbuf [5120,7424) 16x144B
__global__ __launch_bounds__(256, 3)
void motion_grid_main(const float4* __restrict__ sorted,
                      const float* __restrict__ xraw,
                      const uint2* __restrict__ g0v,
                      const uint2* __restrict__ g1v,
                      const unsigned* __restrict__ g2v,
                      const unsigned short* __restrict__ w1p_,
                      const unsigned short* __restrict__ w2p_,
                      const float* __restrict__ b1,
                      const float* __restrict__ b2,
                      float* __restrict__ out, int npts, int sortedMode,
                      int nblk) {
    __shared__ __align__(16) char smem[4 * 7424];
    int bid = blockIdx.x;
    if ((nblk & (NXCD - 1)) == 0) {
        int cpx = nblk / NXCD;
        bid = (bid % NXCD) * cpx + bid / NXCD;
    }
    const int tid = threadIdx.x;
    const int w = tid >> 6, l = tid & 63, c = l & 15, g = l >> 4;
    char* wbase = smem + w * 7424;
    const int p = bid * 256 + tid;

    // ---- point coords ----
    float xv = 0.f, yv = 0.f, zv = 0.f;
    int orig = -1;
    if (p < npts) {
        if (sortedMode) {
            float4 sp = sorted[p];
            xv = sp.x; yv = sp.y; zv = sp.z; orig = __float_as_int(sp.w);
        } else {
            xv = xraw[3 * p]; yv = xraw[3 * p + 1]; zv = xraw[3 * p + 2];
            orig = p;
        }
    }
    float s1[3], c1[3], s2[3], c2[3], s4[3], c4[3];
    trig3(xv, yv, zv, s1, c1, s2, c2, s4, c4);

    // ---- issue ALL 24 row-pair loads ----
    TL4S S0s = tl4_issue<32>(g0v, s1[0], s1[1], s1[2]);
    TL4S S0c = tl4_issue<32>(g0v, c1[0], c1[1], c1[2]);
    TL4S S1s = tl4_issue<64>(g1v, s2[0], s2[1], s2[2]);
    TL4S S1c = tl4_issue<64>(g1v, c2[0], c2[1], c2[2]);
    TL2S S2s = tl2_issue<128>(g2v, s4[0], s4[1], s4[2]);
    TL2S S2c = tl2_issue<128>(g2v, c4[0], c4[1], c4[2]);

    // ---- consume ----
    float f[20];
#pragma unroll
    for (int i = 0; i < 20; ++i) f[i] = 0.f;
    tl4_consume(S0s, f + 0);  tl4_consume(S0c, f + 4);
    tl4_consume(S1s, f + 8);  tl4_consume(S1c, f + 12);
    tl2_consume(S2s, f + 16); tl2_consume(S2c, f + 18);
    {
        uint4* fs = (uint4*)(wbase + l * 80);
        fs[0] = make_uint4(pkrtzu(f[0], f[1]), pkrtzu(f[2], f[3]),
                           pkrtzu(f[4], f[5]), pkrtzu(f[6], f[7]));
        fs[1] = make_uint4(pkrtzu(f[8], f[9]), pkrtzu(f[10], f[11]),
                           pkrtzu(f[12], f[13]), pkrtzu(f[14], f[15]));
        fs[2] = make_uint4(pkrtzu(f[16], f[17]), pkrtzu(f[18], f[19]), 0u, 0u);
        fs[3] = make_uint4(0u, 0u, 0u, 0u);
    }

    // ---- weight fragments + biases ----
    // A layout: row=lane&15, k=(lane>>4)*8+i.  D: col=lane&15, row=(lane>>4)*4+r.
    h8 a1f0 = *(const h8*)(w1p_ + (0 * 16 + c) * 32 + g * 8);
    h8 a1f1 = *(const h8*)(w1p_ + (1 * 16 + c) * 32 + g * 8);
    h8 a1f2 = *(const h8*)(w1p_ + (2 * 16 + c) * 32 + g * 8);
    h8 a1f3 = *(const h8*)(w1p_ + (3 * 16 + c) * 32 + g * 8);
    f4 b1f0 = *(const f4*)(b1 + 0 * 16 + g * 4);
    f4 b1f1 = *(const f4*)(b1 + 1 * 16 + g * 4);
    f4 b1f2 = *(const f4*)(b1 + 2 * 16 + g * 4);
    f4 b1f3 = *(const f4*)(b1 + 3 * 16 + g * 4);
    h8 a20 = *(const h8*)(w2p_ + c * 64 + g * 8);
    h8 a21 = *(const h8*)(w2p_ + c * 64 + 32 + g * 8);
    float b2f0 = (g * 4 + 0 < 7) ? b2[g * 4 + 0] : 0.f;
    float b2f1 = (g * 4 + 1 < 7) ? b2[g * 4 + 1] : 0.f;
    float b2f2 = (g * 4 + 2 < 7) ? b2[g * 4 + 2] : 0.f;
    float b2f3 = (g * 4 + 3 < 7) ? b2[g * 4 + 3] : 0.f;

    // ---- MFMA MLP over the wave's 64 staged points ----
    const f4 zero4 = {0.f, 0.f, 0.f, 0.f};
#pragma unroll
    for (int n = 0; n < 4; ++n) {
        h8 bn = *(const h8*)(wbase + (n * 16 + c) * 80 + g * 16);
        __builtin_amdgcn_s_setprio(1);
        f4 d0 = __builtin_amdgcn_mfma_f32_16x16x32_f16(a1f0, bn, zero4, 0, 0, 0);
        f4 d1 = __builtin_amdgcn_mfma_f32_16x16x32_f16(a1f1, bn, zero4, 0, 0, 0);
        f4 d2m = __builtin_amdgcn_mfma_f32_16x16x32_f16(a1f2, bn, zero4, 0, 0, 0);
        f4 d3 = __builtin_amdgcn_mfma_f32_16x16x32_f16(a1f3, bn, zero4, 0, 0, 0);
        __builtin_amdgcn_s_setprio(0);
        d0 += b1f0; d1 += b1f1; d2m += b1f2; d3 += b1f3;
        {
            float h0 = fmaxf(d0[0], 0.01f * d0[0]), h1 = fmaxf(d0[1], 0.01f * d0[1]);
            float h2 = fmaxf(d0[2], 0.01f * d0[2]), h3 = fmaxf(d0[3], 0.01f * d0[3]);
            *(uint2*)(wbase + 5120 + c * 144 + 0 * 32 + g * 8) =
                make_uint2(pkrtzu(h0, h1), pkrtzu(h2, h3));
            h0 = fmaxf(d1[0], 0.01f * d1[0]); h1 = fmaxf(d1[1], 0.01f * d1[1]);
            h2 = fmaxf(d1[2], 0.01f * d1[2]); h3 = fmaxf(d1[3], 0.01f * d1[3]);
            *(uint2*)(wbase + 5120 + c * 144 + 1 * 32 + g * 8) =
                make_uint2(pkrtzu(h0, h1), pkrtzu(h2, h3));
            h0 = fmaxf(d2m[0], 0.01f * d2m[0]); h1 = fmaxf(d2m[1], 0.01f * d2m[1]);
            h2 = fmaxf(d2m[2], 0.01f * d2m[2]); h3 = fmaxf(d2m[3], 0.01f * d2m[3]);
            *(uint2*)(wbase + 5120 + c * 144 + 2 * 32 + g * 8) =
                make_uint2(pkrtzu(h0, h1), pkrtzu(h2, h3));
            h0 = fmaxf(d3[0], 0.01f * d3[0]); h1 = fmaxf(d3[1], 0.01f * d3[1]);
            h2 = fmaxf(d3[2], 0.01f * d3[2]); h3 = fmaxf(d3[3], 0.01f * d3[3]);
            *(uint2*)(wbase + 5120 + c * 144 + 3 * 32 + g * 8) =
                make_uint2(pkrtzu(h0, h1), pkrtzu(h2, h3));
        }
        h8 hb0 = *(const h8*)(wbase + 5120 + c * 144 + g * 16);
        h8 hb1 = *(const h8*)(wbase + 5120 + c * 144 + 64 + g * 16);
        __builtin_amdgcn_s_setprio(1);
        f4 o2 = __builtin_amdgcn_mfma_f32_16x16x32_f16(a20, hb0, zero4, 0, 0, 0);
        o2 = __builtin_amdgcn_mfma_f32_16x16x32_f16(a21, hb1, o2, 0, 0, 0);
        __builtin_amdgcn_s_setprio(0);
        int og = __shfl(orig, n * 16 + c, 64);
        if (og >= 0 && g < 2) {
            float* op = out + (size_t)og * 7 + g * 4;
            op[0] = o2[0] + b2f0;
            op[1] = o2[1] + b2f1;
            op[2] = o2[2] + b2f2;
            if (g == 0) op[3] = o2[3] + b2f3;
        }
    }
}

extern "C" void kernel_launch(void* const* d_in, const int* in_sizes, int n_in,
                              void* d_out, int out_size, void* d_ws, size_t ws_size,
                              hipStream_t stream) {
    const float* x  = (const float*)d_in[0];
    const float* g0 = (const float*)d_in[1];
    const float* g1 = (const float*)d_in[2];
    const float* g2 = (const float*)d_in[3];
    const float* n0 = (const float*)d_in[4];
    const float* n1 = (const float*)d_in[5];
    const float* n2 = (const float*)d_in[6];
    const float* w1 = (const float*)d_in[7];
    const float* b1 = (const float*)d_in[8];
    const float* w2 = (const float*)d_in[9];
    const float* b2 = (const float*)d_in[10];
    float* out = (float*)d_out;

    const int npts = in_sizes[0] / 3;

    char* ws = (char*)d_ws;
    size_t cur = 0;
    auto alloc = [&](size_t bytes) {
        char* p = ws + cur;
        cur = (cur + bytes + 255) & ~(size_t)255;
        return p;
    };
    uint2*          p0       = (uint2*)         alloc(33792u   * 8 + 64);   // 32*32*33
    uint2*          p1       = (uint2*)         alloc(266240u  * 8 + 64);   // 64*64*65
    unsigned*       p2       = (unsigned*)      alloc(2113536u * 4 + 64);   // 128*128*129
    unsigned short* w1p      = (unsigned short*)alloc(2048 * 2);
    unsigned short* w2p      = (unsigned short*)alloc(1024 * 2);
    unsigned short* counts   = (unsigned short*)alloc((size_t)KB * NB * 2); // 16 MB
    int*            rowsum   = (int*)           alloc(NB * 4);
    float4*         sorted   = (float4*)        alloc((size_t)npts * 16);
    const int useSorted = (ws_size >= cur) ? 1 : 0;

    prep_k<<<PREP_BLOCKS, 256, 0, stream>>>(g0, n0, g1, n1, g2, n2, w1, w2,
                                            p0, p1, p2, w1p, w2p);
    if (useSorted) {
        hist_k<<<KB, 1024, 0, stream>>>(x, counts, npts);
        scan_rows_k<<<NB / 32, 256, 0, stream>>>(counts, rowsum);
        scatter_k<<<KB, 1024, 0, stream>>>(x, counts, rowsum, sorted, npts);
    }

    const int nblk = (npts + 255) / 256;   // 1 point per thread
    motion_grid_main<<<nblk, 256, 0, stream>>>(
        sorted, x, p0, p1, p2, w1p, w2p, b1, b2, out, npts, useSorted, nblk);
}

// Round 21
// 171.881 us; speedup vs baseline: 1.0322x; 1.0322x over previous
//
#include <hip/hip_runtime.h>

// ---------------------------------------------------------------------------
// Motion_Grid: PE(sin/cos @ 3 freqs) -> 6 trilinear samples (3 grids) -> MLP
// Round 21: REVERT to r19 exactly (measured best: 172.3us). r20's KB=256/u16
// sort regressed +7us (hist/scatter are prologue-bound at 1 block/CU, not
// CU-count bound). Final architecture:
//   prep:   pack grids to f16 x-padded [z][y][xp] + f16 MFMA-padded weights
//   sort:   atomic-free bucket sort, bins 8x64x64 (row-clustered: y,z fine ->
//           wave's 64 pts share grid rows -> TA merges same-line lanes; this
//           lever cut main 152->130->114us and FETCH 139->99->60MB, r18/r19)
//   main:   1 pt/thread, 24 fused row-pair gathers issued up front, per-wave
//           MFMA MLP (mfma_f32_16x16x32_f16) on 64-pt batches, no barriers
// ---------------------------------------------------------------------------

#define NB 32768     // 8(x) x 64(y) x 64(z) bins over raw x in [0,1)^3
#define KB 128       // counting/scatter chunks (= scan-matrix columns)
#define NXCD 8

typedef _Float16 f16x2 __attribute__((ext_vector_type(2)));
typedef __fp16  h8    __attribute__((ext_vector_type(8)));   // MFMA A/B frag
typedef float   f4    __attribute__((ext_vector_type(4)));   // MFMA C/D frag

__device__ __forceinline__ f16x2 pkrtz(float a, float b) {
    return __builtin_bit_cast(f16x2, __builtin_amdgcn_cvt_pkrtz(a, b));
}
__device__ __forceinline__ unsigned pkrtzu(float a, float b) {
    return __builtin_bit_cast(unsigned, __builtin_amdgcn_cvt_pkrtz(a, b));
}
__device__ __forceinline__ float fdot2(f16x2 a, f16x2 b, float c) {
    return __builtin_amdgcn_fdot2(a, b, c, false);
}
__device__ __forceinline__ f16x2 u2h(unsigned u) { return __builtin_bit_cast(f16x2, u); }

// x coarse (3b: intra-line dim), y fine (6b), z fine (6b); x-fastest order.
__device__ __forceinline__ int bin_of(float xv, float yv, float zv) {
    int qx = min(max((int)(xv * 8.f), 0), 7);
    int qy = min(max((int)(yv * 64.f), 0), 63);
    int qz = min(max((int)(zv * 64.f), 0), 63);
    return (qz << 9) | (qy << 3) | qx;
}

// ---- Fused prep: pack x-padded f16 grids | padded weights ------------------
// Padded grid layout: [z][y][xp], xp in [0,S], cell (z,y,xp) = src (z,y,max(xp-1,0)).
#define PREP_BLOCKS 9440

__global__ __launch_bounds__(256)
void prep_k(const float* __restrict__ g0, const float* __restrict__ n0,
            const float* __restrict__ g1, const float* __restrict__ n1,
            const float* __restrict__ g2, const float* __restrict__ n2,
            const float* __restrict__ w1, const float* __restrict__ w2,
            uint2* __restrict__ p0, uint2* __restrict__ p1,
            unsigned* __restrict__ p2,
            unsigned short* __restrict__ w1p, unsigned short* __restrict__ w2p) {
    const int b = blockIdx.x, t = threadIdx.x;
    if (b < 8256) {                      // grid2: 128*128*129 padded cells
        int i = b * 256 + t;
        if (i < 2113536) {
            int z = i / 16512, rem = i % 16512;
            int y = rem / 129, xp = rem % 129;
            int v = (z * 128 + y) * 128 + max(xp - 1, 0);
            p2[i] = pkrtzu(g2[v] + n2[v], g2[2097152 + v] + n2[2097152 + v]);
        }
    } else if (b < 9296) {               // grid1: 64*64*65 padded cells
        int i = (b - 8256) * 256 + t;
        if (i < 266240) {
            int z = i / 4160, rem = i % 4160;
            int y = rem / 65, xp = rem % 65;
            int v = (z * 64 + y) * 64 + max(xp - 1, 0);
            uint2 r;
            r.x = pkrtzu(g1[v] + n1[v], g1[262144 + v] + n1[262144 + v]);
            r.y = pkrtzu(g1[524288 + v] + n1[524288 + v], g1[786432 + v] + n1[786432 + v]);
            p1[i] = r;
        }
    } else if (b < 9428) {               // grid0: 32*32*33 padded cells
        int i = (b - 9296) * 256 + t;
        if (i < 33792) {
            int z = i / 1056, rem = i % 1056;
            int y = rem / 33, xp = rem % 33;
            int v = (z * 32 + y) * 32 + max(xp - 1, 0);
            uint2 r;
            r.x = pkrtzu(g0[v] + n0[v], g0[32768 + v] + n0[32768 + v]);
            r.y = pkrtzu(g0[65536 + v] + n0[65536 + v], g0[98304 + v] + n0[98304 + v]);
            p0[i] = r;
        }
    } else {                             // weights: 2048 + 1024 halves
        int i = (b - 9428) * 256 + t;
        if (i < 2048) {                  // w1p[j][k], K padded 20->32
            int j = i >> 5, k = i & 31;
            float v = (k < 20) ? w1[j * 20 + k] : 0.f;
            w1p[i] = __builtin_bit_cast(unsigned short, (_Float16)v);
        } else if (i < 3072) {           // w2p[o][jj], M padded 7->16
            int i2 = i - 2048;
            int o = i2 >> 6, jj = i2 & 63;
            float v = (o < 7) ? w2[o * 64 + jj] : 0.f;
            w2p[i2] = __builtin_bit_cast(unsigned short, (_Float16)v);
        }
    }
}

// ---- Histogram: standalone, dual-u16 LDS counters (64 KB) ------------------
__global__ __launch_bounds__(1024)
void hist_k(const float* __restrict__ x, int* __restrict__ counts, int npts) {
    __shared__ unsigned h32[NB / 2];   // 64 KB: two u16 counters per uint
    const int t = threadIdx.x, b = blockIdx.x;
    for (int i = t; i < NB / 2; i += 1024) h32[i] = 0u;
    __syncthreads();
    const int chunk = (npts + KB - 1) / KB;
    const int s = b * chunk, e = min(s + chunk, npts);
    for (int p = s + t; p < e; p += 1024) {
        int bin = bin_of(x[3 * p], x[3 * p + 1], x[3 * p + 2]);
        atomicAdd(&h32[bin >> 1], 1u << ((bin & 1) * 16));  // LDS atomic
    }
    __syncthreads();
    for (int i = t; i < NB; i += 1024)
        counts[b * NB + i] = (int)((h32[i >> 1] >> ((i & 1) * 16)) & 0xffffu);
}

// ---- Cross-block scan, LDS-tiled, IN-PLACE (offs == counts). ---------------
__global__ __launch_bounds__(256)
void scan_rows_k(int* __restrict__ counts, int* __restrict__ rowsum) {
    __shared__ int tile[KB][32];   // 16 KB
    const int g = blockIdx.x, t = threadIdx.x;
    for (int idx = t; idx < KB * 32; idx += 256) {
        int b = idx >> 5, j = idx & 31;
        tile[b][j] = counts[b * NB + g * 32 + j];
    }
    __syncthreads();
    if (t < 32) {
        int run = 0;
#pragma unroll 8
        for (int b = 0; b < KB; ++b) {
            int v = tile[b][t];
            tile[b][t] = run;
            run += v;
        }
        rowsum[g * 32 + t] = run;
    }
    __syncthreads();
    for (int idx = t; idx < KB * 32; idx += 256) {
        int b = idx >> 5, j = idx & 31;
        counts[b * NB + g * 32 + j] = tile[b][j];   // in-place exclusive
    }
}

// ---- Scatter: shfl-based top-scan of rowsum + LDS-ranked scatter -----------
__global__ __launch_bounds__(1024)
void scatter_k(const float* __restrict__ x, const int* __restrict__ offs,
               const int* __restrict__ rowsum, float4* __restrict__ sorted,
               int npts) {
    __shared__ int base[NB];     // 128 KB
    __shared__ int wsum[16];
    const int t = threadIdx.x, b = blockIdx.x;
    const int lane = t & 63;

    // binbase = exclusive scan of rowsum[NB], 32 entries/thread, wave-scan.
    const int t32 = t * 32;
    int s32 = 0;
    for (int i = 0; i < 32; ++i) s32 += rowsum[t32 + i];
    int inc = s32;
    for (int d = 1; d < 64; d <<= 1) {
        int o = __shfl_up(inc, d, 64);
        if (lane >= d) inc += o;
    }
    if (lane == 63) wsum[t >> 6] = inc;
    __syncthreads();
    if (t == 0) {
        int acc = 0;
        for (int i = 0; i < 16; ++i) { int v = wsum[i]; wsum[i] = acc; acc += v; }
    }
    __syncthreads();
    int run = wsum[t >> 6] + inc - s32;
    for (int i = 0; i < 32; ++i) {
        int v = rowsum[t32 + i];
        base[t32 + i] = run;
        run += v;
    }
    __syncthreads();
    for (int i = t; i < NB; i += 1024) base[i] += offs[b * NB + i];  // coalesced
    __syncthreads();

    const int chunk = (npts + KB - 1) / KB;
    const int s = b * chunk, e = min(s + chunk, npts);
    for (int p = s + t; p < e; p += 1024) {
        float xv = x[3 * p], yv = x[3 * p + 1], zv = x[3 * p + 2];
        int pos = atomicAdd(&base[bin_of(xv, yv, zv)], 1);  // LDS atomic
        float4 v; v.x = xv; v.y = yv; v.z = zv; v.w = __int_as_float(p);
        sorted[pos] = v;
    }
}

// ---- Trilinear gather on x-padded grid, fused row-pair loads ---------------
template<int S>
__device__ __forceinline__ void tl_setup(float cx, float cy, float cz,
        int& o00, int& o01, int& o10, int& o11,
        f16x2& w00, f16x2& w01, f16x2& w10, f16x2& w11) {
    const float hs = (float)S * 0.5f;
    float gx = fmaf(cx, hs, hs - 0.5f);
    float gy = fmaf(cy, hs, hs - 0.5f);
    float gz = fmaf(cz, hs, hs - 0.5f);
    float fx = floorf(gx), fy = floorf(gy), fz = floorf(gz);
    float tx = gx - fx, ty = gy - fy, tz = gz - fz;
    int x0 = (int)fx, y0 = (int)fy, z0 = (int)fz;
    float wx0 = (1.f - tx) * ((x0 >= 0)    ? 1.f : 0.f);
    float wx1 = tx         * ((x0 + 1 < S) ? 1.f : 0.f);
    float wy0 = (1.f - ty) * ((y0 >= 0)    ? 1.f : 0.f);
    float wy1 = ty         * ((y0 + 1 < S) ? 1.f : 0.f);
    float wz0 = (1.f - tz) * ((z0 >= 0)    ? 1.f : 0.f);
    float wz1 = tz         * ((z0 + 1 < S) ? 1.f : 0.f);
    const int xb = x0 + 1;                 // padded-x index, always valid
    f16x2 wx2 = pkrtz(wx0, wx1);
    int ys0 = max(y0, 0), ys1 = min(y0 + 1, S - 1);
    int zs0 = max(z0, 0), zs1 = min(z0 + 1, S - 1);
    o00 = (zs0 * S + ys0) * (S + 1) + xb;
    o01 = (zs0 * S + ys1) * (S + 1) + xb;
    o10 = (zs1 * S + ys0) * (S + 1) + xb;
    o11 = (zs1 * S + ys1) * (S + 1) + xb;
    float a00 = wz0 * wy0, a01 = wz0 * wy1, a10 = wz1 * wy0, a11 = wz1 * wy1;
    w00 = pkrtz(a00, a00) * wx2;
    w01 = pkrtz(a01, a01) * wx2;
    w10 = pkrtz(a10, a10) * wx2;
    w11 = pkrtz(a11, a11) * wx2;
}

struct TL4S {
    uint4 r00, r01, r10, r11;
    f16x2 w00, w01, w10, w11;
};
template<int S>
__device__ __forceinline__ TL4S tl4_issue(const uint2* __restrict__ vol,
                                          float cx, float cy, float cz) {
    TL4S r; int o00, o01, o10, o11;
    tl_setup<S>(cx, cy, cz, o00, o01, o10, o11, r.w00, r.w01, r.w10, r.w11);
    r.r00 = *reinterpret_cast<const uint4*>(vol + o00);
    r.r01 = *reinterpret_cast<const uint4*>(vol + o01);
    r.r10 = *reinterpret_cast<const uint4*>(vol + o10);
    r.r11 = *reinterpret_cast<const uint4*>(vol + o11);
    return r;
}
#define TL4_ROW(s, R, WP, f) { uint4 r = (s).R; \
    unsigned pc0 = __builtin_amdgcn_perm(r.z, r.x, 0x05040100u); \
    unsigned pc1 = __builtin_amdgcn_perm(r.z, r.x, 0x07060302u); \
    unsigned pc2 = __builtin_amdgcn_perm(r.w, r.y, 0x05040100u); \
    unsigned pc3 = __builtin_amdgcn_perm(r.w, r.y, 0x07060302u); \
    (f)[0] = fdot2((s).WP, u2h(pc0), (f)[0]); (f)[1] = fdot2((s).WP, u2h(pc1), (f)[1]); \
    (f)[2] = fdot2((s).WP, u2h(pc2), (f)[2]); (f)[3] = fdot2((s).WP, u2h(pc3), (f)[3]); }
__device__ __forceinline__ void tl4_consume(const TL4S& s, float* f) {
    TL4_ROW(s, r00, w00, f) TL4_ROW(s, r01, w01, f)
    TL4_ROW(s, r10, w10, f) TL4_ROW(s, r11, w11, f)
}

struct TL2S {
    uint2 r00, r01, r10, r11;
    f16x2 w00, w01, w10, w11;
};
template<int S>
__device__ __forceinline__ TL2S tl2_issue(const unsigned* __restrict__ vol,
                                          float cx, float cy, float cz) {
    TL2S r; int o00, o01, o10, o11;
    tl_setup<S>(cx, cy, cz, o00, o01, o10, o11, r.w00, r.w01, r.w10, r.w11);
    r.r00 = *reinterpret_cast<const uint2*>(vol + o00);
    r.r01 = *reinterpret_cast<const uint2*>(vol + o01);
    r.r10 = *reinterpret_cast<const uint2*>(vol + o10);
    r.r11 = *reinterpret_cast<const uint2*>(vol + o11);
    return r;
}
#define TL2_ROW(s, R, WP, f) { uint2 r = (s).R; \
    unsigned pc0 = __builtin_amdgcn_perm(r.y, r.x, 0x05040100u); \
    unsigned pc1 = __builtin_amdgcn_perm(r.y, r.x, 0x07060302u); \
    (f)[0] = fdot2((s).WP, u2h(pc0), (f)[0]); (f)[1] = fdot2((s).WP, u2h(pc1), (f)[1]); }
__device__ __forceinline__ void tl2_consume(const TL2S& s, float* f) {
    TL2_ROW(s, r00, w00, f) TL2_ROW(s, r01, w01, f)
    TL2_ROW(s, r10, w10, f) TL2_ROW(s, r11, w11, f)
}

__device__ __forceinline__ void trig3(float x, float y, float z,
        float* s1, float* c1, float* s2, float* c2, float* s4, float* c4) {
    const float v[3] = {x, y, z};
#pragma unroll
    for (int d = 0; d < 3; ++d) {
        float sa = __builtin_amdgcn_sinf(0.5f * v[d]);
        float ca = __builtin_amdgcn_cosf(0.5f * v[d]);
        s1[d] = sa; c1[d] = ca;
        float sb = 2.f * sa * ca, cb = fmaf(-2.f * sa, sa, 1.f);
        s2[d] = sb; c2[d] = cb;
        s4[d] = 2.f * sb * cb; c4[d] = fmaf(-2.f * sb, sb, 1.f);
    }
}

// ---- Main: 1 pt/thread, per-wave MFMA MLP, wave-local LDS ------------------
// Per-wave LDS 7424 B: fbuf [0,5120) 64x80B | hbuf [5120,7424) 16x144B
__global__ __launch_bounds__(256, 3)
void motion_grid_main(const float4* __restrict__ sorted,
                      const float* __restrict__ xraw,
                      const uint2* __restrict__ g0v,
                      const uint2* __restrict__ g1v,
                      const unsigned* __restrict__ g2v,
                      const unsigned short* __restrict__ w1p_,
                      const unsigned short* __restrict__ w2p_,
                      const float* __restrict__ b1,
                      const float* __restrict__ b2,
                      float* __restrict__ out, int npts, int sortedMode,
                      int nblk) {
    __shared__ __align__(16) char smem[4 * 7424];
    int bid = blockIdx.x;
    if ((nblk & (NXCD - 1)) == 0) {
        int cpx = nblk / NXCD;
        bid = (bid % NXCD) * cpx + bid / NXCD;
    }
    const int tid = threadIdx.x;
    const int w = tid >> 6, l = tid & 63, c = l & 15, g = l >> 4;
    char* wbase = smem + w * 7424;
    const int p = bid * 256 + tid;

    // ---- point coords ----
    float xv = 0.f, yv = 0.f, zv = 0.f;
    int orig = -1;
    if (p < npts) {
        if (sortedMode) {
            float4 sp = sorted[p];
            xv = sp.x; yv = sp.y; zv = sp.z; orig = __float_as_int(sp.w);
        } else {
            xv = xraw[3 * p]; yv = xraw[3 * p + 1]; zv = xraw[3 * p + 2];
            orig = p;
        }
    }
    float s1[3], c1[3], s2[3], c2[3], s4[3], c4[3];
    trig3(xv, yv, zv, s1, c1, s2, c2, s4, c4);

    // ---- issue ALL 24 row-pair loads ----
    TL4S S0s = tl4_issue<32>(g0v, s1[0], s1[1], s1[2]);
    TL4S S0c = tl4_issue<32>(g0v, c1[0], c1[1], c1[2]);
    TL4S S1s = tl4_issue<64>(g1v, s2[0], s2[1], s2[2]);
    TL4S S1c = tl4_issue<64>(g1v, c2[0], c2[1], c2[2]);
    TL2S S2s = tl2_issue<128>(g2v, s4[0], s4[1], s4[2]);
    TL2S S2c = tl2_issue<128>(g2v, c4[0], c4[1], c4[2]);

    // ---- consume ----
    float f[20];
#pragma unroll
    for (int i = 0; i < 20; ++i) f[i] = 0.f;
    tl4_consume(S0s, f + 0);  tl4_consume(S0c, f + 4);
    tl4_consume(S1s, f + 8);  tl4_consume(S1c, f + 12);
    tl2_consume(S2s, f + 16); tl2_consume(S2c, f + 18);
    {
        uint4* fs = (uint4*)(wbase + l * 80);
        fs[0] = make_uint4(pkrtzu(f[0], f[1]), pkrtzu(f[2], f[3]),
                           pkrtzu(f[4], f[5]), pkrtzu(f[6], f[7]));
        fs[1] = make_uint4(pkrtzu(f[8], f[9]), pkrtzu(f[10], f[11]),
                           pkrtzu(f[12], f[13]), pkrtzu(f[14], f[15]));
        fs[2] = make_uint4(pkrtzu(f[16], f[17]), pkrtzu(f[18], f[19]), 0u, 0u);
        fs[3] = make_uint4(0u, 0u, 0u, 0u);
    }

    // ---- weight fragments + biases ----
    // A layout: row=lane&15, k=(lane>>4)*8+i.  D: col=lane&15, row=(lane>>4)*4+r.
    h8 a1f0 = *(const h8*)(w1p_ + (0 * 16 + c) * 32 + g * 8);
    h8 a1f1 = *(const h8*)(w1p_ + (1 * 16 + c) * 32 + g * 8);
    h8 a1f2 = *(const h8*)(w1p_ + (2 * 16 + c) * 32 + g * 8);
    h8 a1f3 = *(const h8*)(w1p_ + (3 * 16 + c) * 32 + g * 8);
    f4 b1f0 = *(const f4*)(b1 + 0 * 16 + g * 4);
    f4 b1f1 = *(const f4*)(b1 + 1 * 16 + g * 4);
    f4 b1f2 = *(const f4*)(b1 + 2 * 16 + g * 4);
    f4 b1f3 = *(const f4*)(b1 + 3 * 16 + g * 4);
    h8 a20 = *(const h8*)(w2p_ + c * 64 + g * 8);
    h8 a21 = *(const h8*)(w2p_ + c * 64 + 32 + g * 8);
    float b2f0 = (g * 4 + 0 < 7) ? b2[g * 4 + 0] : 0.f;
    float b2f1 = (g * 4 + 1 < 7) ? b2[g * 4 + 1] : 0.f;
    float b2f2 = (g * 4 + 2 < 7) ? b2[g * 4 + 2] : 0.f;
    float b2f3 = (g * 4 + 3 < 7) ? b2[g * 4 + 3] : 0.f;

    // ---- MFMA MLP over the wave's 64 staged points ----
    const f4 zero4 = {0.f, 0.f, 0.f, 0.f};
#pragma unroll
    for (int n = 0; n < 4; ++n) {
        h8 bn = *(const h8*)(wbase + (n * 16 + c) * 80 + g * 16);
        __builtin_amdgcn_s_setprio(1);
        f4 d0 = __builtin_amdgcn_mfma_f32_16x16x32_f16(a1f0, bn, zero4, 0, 0, 0);
        f4 d1 = __builtin_amdgcn_mfma_f32_16x16x32_f16(a1f1, bn, zero4, 0, 0, 0);
        f4 d2m = __builtin_amdgcn_mfma_f32_16x16x32_f16(a1f2, bn, zero4, 0, 0, 0);
        f4 d3 = __builtin_amdgcn_mfma_f32_16x16x32_f16(a1f3, bn, zero4, 0, 0, 0);
        __builtin_amdgcn_s_setprio(0);
        d0 += b1f0; d1 += b1f1; d2m += b1f2; d3 += b1f3;
        {
            float h0 = fmaxf(d0[0], 0.01f * d0[0]), h1 = fmaxf(d0[1], 0.01f * d0[1]);
            float h2 = fmaxf(d0[2], 0.01f * d0[2]), h3 = fmaxf(d0[3], 0.01f * d0[3]);
            *(uint2*)(wbase + 5120 + c * 144 + 0 * 32 + g * 8) =
                make_uint2(pkrtzu(h0, h1), pkrtzu(h2, h3));
            h0 = fmaxf(d1[0], 0.01f * d1[0]); h1 = fmaxf(d1[1], 0.01f * d1[1]);
            h2 = fmaxf(d1[2], 0.01f * d1[2]); h3 = fmaxf(d1[3], 0.01f * d1[3]);
            *(uint2*)(wbase + 5120 + c * 144 + 1 * 32 + g * 8) =
                make_uint2(pkrtzu(h0, h1), pkrtzu(h2, h3));
            h0 = fmaxf(d2m[0], 0.01f * d2m[0]); h1 = fmaxf(d2m[1], 0.01f * d2m[1]);
            h2 = fmaxf(d2m[2], 0.01f * d2m[2]); h3 = fmaxf(d2m[3], 0.01f * d2m[3]);
            *(uint2*)(wbase + 5120 + c * 144 + 2 * 32 + g * 8) =
                make_uint2(pkrtzu(h0, h1), pkrtzu(h2, h3));
            h0 = fmaxf(d3[0], 0.01f * d3[0]); h1 = fmaxf(d3[1], 0.01f * d3[1]);
            h2 = fmaxf(d3[2], 0.01f * d3[2]); h3 = fmaxf(d3[3], 0.01f * d3[3]);
            *(uint2*)(wbase + 5120 + c * 144 + 3 * 32 + g * 8) =
                make_uint2(pkrtzu(h0, h1), pkrtzu(h2, h3));
        }
        h8 hb0 = *(const h8*)(wbase + 5120 + c * 144 + g * 16);
        h8 hb1 = *(const h8*)(wbase + 5120 + c * 144 + 64 + g * 16);
        __builtin_amdgcn_s_setprio(1);
        f4 o2 = __builtin_amdgcn_mfma_f32_16x16x32_f16(a20, hb0, zero4, 0, 0, 0);
        o2 = __builtin_amdgcn_mfma_f32_16x16x32_f16(a21, hb1, o2, 0, 0, 0);
        __builtin_amdgcn_s_setprio(0);
        int og = __shfl(orig, n * 16 + c, 64);
        if (og >= 0 && g < 2) {
            float* op = out + (size_t)og * 7 + g * 4;
            op[0] = o2[0] + b2f0;
            op[1] = o2[1] + b2f1;
            op[2] = o2[2] + b2f2;
            if (g == 0) op[3] = o2[3] + b2f3;
        }
    }
}

extern "C" void kernel_launch(void* const* d_in, const int* in_sizes, int n_in,
                              void* d_out, int out_size, void* d_ws, size_t ws_size,
                              hipStream_t stream) {
    const float* x  = (const float*)d_in[0];
    const float* g0 = (const float*)d_in[1];
    const float* g1 = (const float*)d_in[2];
    const float* g2 = (const float*)d_in[3];
    const float* n0 = (const float*)d_in[4];
    const float* n1 = (const float*)d_in[5];
    const float* n2 = (const float*)d_in[6];
    const float* w1 = (const float*)d_in[7];
    const float* b1 = (const float*)d_in[8];
    const float* w2 = (const float*)d_in[9];
    const float* b2 = (const float*)d_in[10];
    float* out = (float*)d_out;

    const int npts = in_sizes[0] / 3;

    char* ws = (char*)d_ws;
    size_t cur = 0;
    auto alloc = [&](size_t bytes) {
        char* p = ws + cur;
        cur = (cur + bytes + 255) & ~(size_t)255;
        return p;
    };
    uint2*          p0       = (uint2*)         alloc(33792u   * 8 + 64);   // 32*32*33
    uint2*          p1       = (uint2*)         alloc(266240u  * 8 + 64);   // 64*64*65
    unsigned*       p2       = (unsigned*)      alloc(2113536u * 4 + 64);   // 128*128*129
    unsigned short* w1p      = (unsigned short*)alloc(2048 * 2);
    unsigned short* w2p      = (unsigned short*)alloc(1024 * 2);
    int*            counts   = (int*)           alloc((size_t)KB * NB * 4); // 16 MB
    int*            rowsum   = (int*)           alloc(NB * 4);
    float4*         sorted   = (float4*)        alloc((size_t)npts * 16);
    const int useSorted = (ws_size >= cur) ? 1 : 0;

    prep_k<<<PREP_BLOCKS, 256, 0, stream>>>(g0, n0, g1, n1, g2, n2, w1, w2,
                                            p0, p1, p2, w1p, w2p);
    if (useSorted) {
        hist_k<<<KB, 1024, 0, stream>>>(x, counts, npts);
        scan_rows_k<<<NB / 32, 256, 0, stream>>>(counts, rowsum);
        scatter_k<<<KB, 1024, 0, stream>>>(x, counts, rowsum, sorted, npts);
    }

    const int nblk = (npts + 255) / 256;   // 1 point per thread
    motion_grid_main<<<nblk, 256, 0, stream>>>(
        sorted, x, p0, p1, p2, w1p, w2p, b1, b2, out, npts, useSorted, nblk);
}